// Round 3
// baseline (28.556 us; speedup 1.0000x reference)
//
#include <hip/hip_runtime.h>
#include <hip/hip_bf16.h>

// LearnableInterpolation: out[b,t,n] = sum_o softmax_o(-3*(tpos[o,n]-tgt[t])^2) * x[b,o,n]
// B=32, L_org=L_to=2048, N=21. Softmax over o is a near-delta -> 17-tap window.
//
// R3: kernel1 transposes x -> xt[N,B,L] (coalesced both sides).
// kernel2: block = (64-t-tile, b) covering ALL 21 channels; per-channel LDS
// windows (stride 113, odd -> conflict-free); outputs staged in LDS and
// written as contiguous float4 (R2's stride-84B scattered stores removed).

constexpr int LORG  = 2048;
constexpr int LTO   = 2048;
constexpr int NCH   = 21;
constexpr int BATCH = 32;
constexpr int W     = 8;
constexpr int NW    = 2 * W + 1;   // 17 taps
constexpr int TT    = 64;          // t-tile per block
constexpr int XCAP  = 112;         // max window span: ceil(63/0.7)+1+17 = 108
constexpr int XSTR  = 113;         // odd stride -> LDS banks spread

constexpr float MIN_RATIO = 0.7f, MAX_RATIO = 1.3f;
constexpr float MIN_BIAS  = -4.0f, MAX_BIAS = 4.0f;
constexpr float NEG3LOG2E = -3.0f * 1.4426950408889634f;  // softmax scale, log2 domain

__device__ __forceinline__ int compute_o0(float tg, float bb, float inv_r) {
    const float ocf = (float)LORG + (tg - bb) * inv_r;
    int o0 = (int)floorf(ocf + 0.5f) - W;
    return max(0, min(LORG - NW, o0));
}

// ---------------- kernel 1: transpose x[B,LORG,NCH] -> xt[NCH,BATCH,LORG] ---
__global__ __launch_bounds__(256) void li_transpose(
    const float* __restrict__ x, float* __restrict__ xt)
{
    const int b  = blockIdx.y;
    const int o0 = blockIdx.x * 64;
    __shared__ float tile[64 * NCH];
    const float* src = x + ((size_t)b * LORG + o0) * NCH;
    for (int i = threadIdx.x; i < 64 * NCH; i += 256) tile[i] = src[i];
    __syncthreads();
    for (int j = threadIdx.x; j < 64 * NCH; j += 256) {
        const int n = j >> 6, k = j & 63;              // lane==k -> coalesced write
        xt[((size_t)(n * BATCH + b)) * LORG + o0 + k] = tile[k * NCH + n];
    }
}

// ---------------- kernel 2: main interpolation ------------------------------
__global__ __launch_bounds__(256) void li_interp(
    const float* __restrict__ xt,
    const float* __restrict__ rmo,
    const float* __restrict__ bias,
    float* __restrict__ out)
{
    const int t0  = blockIdx.x * TT;
    const int b   = blockIdx.y;
    const int tid = threadIdx.x;

    __shared__ float xs[NCH][XSTR];
    __shared__ __align__(16) float osh[TT * NCH];      // 1344 floats
    __shared__ float rsh[NCH], bsh[NCH], irsh[NCH];
    __shared__ int   olo[NCH];

    if (tid < NCH) {
        const float r  = fminf(fmaxf(rmo[tid] + 1.0f, MIN_RATIO), MAX_RATIO);
        const float bb = fminf(fmaxf(bias[tid], MIN_BIAS), MAX_BIAS);
        rsh[tid]  = r;
        bsh[tid]  = bb;
        irsh[tid] = 1.0f / r;
    }
    __syncthreads();

    // stage per-channel windows: wave w handles channels w, w+4, ...
    const int wave = tid >> 6, lane = tid & 63;
    for (int n = wave; n < NCH; n += 4) {
        const float bb = bsh[n], ir = irsh[n];
        const int lo  = compute_o0((float)(t0 - LTO), bb, ir);
        const int hi  = compute_o0((float)(t0 + TT - 1 - LTO), bb, ir);
        const int len = min(XCAP, hi + NW - lo);
        if (lane == 0) olo[n] = lo;
        const float* col = xt + ((size_t)(n * BATCH + b)) * LORG + lo;
        for (int i = lane; i < len; i += 64) xs[n][i] = col[i];
    }
    __syncthreads();

    // compute: each thread ~5-6 (t,n) outputs
    for (int p = tid; p < TT * NCH; p += 256) {
        const int n  = p % NCH;
        const int tl = p / NCH;
        const float r  = rsh[n];
        const float bb = bsh[n];
        const float ir = irsh[n];
        const float tg = (float)(t0 + tl - LTO);
        const int   o0 = compute_o0(tg, bb, ir);
        float d = (float)(o0 - LORG) * r + bb - tg;   // d_j = d0 + j*r

        float e[NW];
        float m = -1e30f;
        #pragma unroll
        for (int j = 0; j < NW; ++j) {
            e[j] = NEG3LOG2E * d * d;                 // log2-domain exponent
            m = fmaxf(m, e[j]);
            d += r;
        }
        const int base = o0 - olo[n];
        float s = 0.0f, acc = 0.0f;
        #pragma unroll
        for (int j = 0; j < NW; ++j) {
            const float wgt = exp2f(e[j] - m);        // native v_exp_f32
            s += wgt;
            acc = fmaf(wgt, xs[n][base + j], acc);
        }
        osh[p] = acc * __builtin_amdgcn_rcpf(s);
    }
    __syncthreads();

    // coalesced float4 output: 1344 floats = 336 float4 per block
    float4* dst = (float4*)(out + ((size_t)b * LTO + t0) * NCH);
    const float4* src4 = (const float4*)osh;
    for (int i = tid; i < TT * NCH / 4; i += 256) dst[i] = src4[i];
}

// ---------------- fallback (R1 kernel) if ws too small ----------------------
__global__ __launch_bounds__(256) void li_kernel_fallback(
    const float* __restrict__ x,
    const float* __restrict__ rmo,
    const float* __restrict__ bias,
    float* __restrict__ out)
{
    const int t   = blockIdx.x;
    const int tid = threadIdx.x;
    __shared__ float wsh[NCH][NW];
    __shared__ int   osh[NCH];

    if (tid < NCH) {
        const float ratio = fminf(fmaxf(rmo[tid] + 1.0f, MIN_RATIO), MAX_RATIO);
        const float bb    = fminf(fmaxf(bias[tid], MIN_BIAS), MAX_BIAS);
        const float tg    = (float)(t - LTO);
        const float ocf   = (float)LORG + (tg - bb) / ratio;
        int o0 = (int)floorf(ocf + 0.5f) - W;
        o0 = max(0, min(LORG - NW, o0));
        osh[tid] = o0;
        float ex[NW];
        float m = -1e30f;
        #pragma unroll
        for (int j = 0; j < NW; ++j) {
            const float tp = (float)(o0 + j - LORG) * ratio + bb;
            const float dd = tp - tg;
            ex[j] = -3.0f * dd * dd;
            m = fmaxf(m, ex[j]);
        }
        float s = 0.0f;
        #pragma unroll
        for (int j = 0; j < NW; ++j) { ex[j] = __expf(ex[j] - m); s += ex[j]; }
        const float inv = 1.0f / s;
        #pragma unroll
        for (int j = 0; j < NW; ++j) wsh[tid][j] = ex[j] * inv;
    }
    __syncthreads();

    for (int idx = tid; idx < BATCH * NCH; idx += blockDim.x) {
        const int bq = idx / NCH;
        const int n  = idx - bq * NCH;
        const int o0 = osh[n];
        const float* xp = x + ((size_t)bq * LORG + o0) * NCH + n;
        float acc = 0.0f;
        #pragma unroll
        for (int j = 0; j < NW; ++j)
            acc = fmaf(wsh[n][j], xp[j * NCH], acc);
        out[((size_t)bq * LTO + t) * NCH + n] = acc;
    }
}

extern "C" void kernel_launch(void* const* d_in, const int* in_sizes, int n_in,
                              void* d_out, int out_size, void* d_ws, size_t ws_size,
                              hipStream_t stream) {
    const float* x    = (const float*)d_in[0];
    const float* rmo  = (const float*)d_in[1];
    const float* bias = (const float*)d_in[2];
    float* out = (float*)d_out;

    const size_t xt_bytes = (size_t)NCH * BATCH * LORG * sizeof(float);
    if (ws_size >= xt_bytes) {
        float* xt = (float*)d_ws;
        li_transpose<<<dim3(LORG / 64, BATCH), 256, 0, stream>>>(x, xt);
        li_interp<<<dim3(LTO / TT, BATCH), 256, 0, stream>>>(xt, rmo, bias, out);
    } else {
        li_kernel_fallback<<<LTO, 256, 0, stream>>>(x, rmo, bias, out);
    }
}

// Round 4
// 17.670 us; speedup vs baseline: 1.6161x; 1.6161x over previous
//
#include <hip/hip_runtime.h>
#include <hip/hip_bf16.h>

// LearnableInterpolation: out[b,t,n] = sum_o softmax_o(-3*(tpos[o,n]-tgt[t])^2) * x[b,o,n]
// B=32, L_org=L_to=2048, N=21. Softmax over o is a near-delta -> 17-tap window.
//
// R4: SINGLE fused kernel, no transpose. Key fact: the o-window and weights
// depend only on (t, n), not on b. Block = (n, 64-wide t-tile, 16-batch half):
//  - each thread computes the 17 softmax weights for its own tl ONCE into
//    registers (amortized over batches; analytic max, no fmax chain),
//  - the 16 per-batch windows (~107 floats each) are gathered into LDS
//    (stride-84B scalar gather; total L2 transaction volume ~148MB ~= what
//    R1 sustained in 43us for 1.5GB, so ~5us here),
//  - 4 outputs/thread, 17 LDS FMAs each.
// 1344 blocks (~21 waves/CU) for latency hiding; XCD-swizzled so blocks
// sharing x-rows (same t-tile, all n) land on the same XCD L2.

constexpr int LORG  = 2048;
constexpr int LTO   = 2048;
constexpr int NCH   = 21;
constexpr int BATCH = 32;
constexpr int W     = 8;
constexpr int NW    = 2 * W + 1;   // 17 taps
constexpr int TT    = 64;          // t-tile
constexpr int BH    = 16;          // batches per block (half)
constexpr int XSTR  = 113;         // LDS stride (odd): window len <= 107
constexpr int NBLK  = NCH * (LTO / TT) * (BATCH / BH);   // 21*32*2 = 1344

constexpr float MIN_RATIO = 0.7f, MAX_RATIO = 1.3f;
constexpr float MIN_BIAS  = -4.0f, MAX_BIAS = 4.0f;
constexpr float NEG3LOG2E = -3.0f * 1.4426950408889634f;  // log2-domain scale

__device__ __forceinline__ int compute_o0(float tg, float bb, float ir) {
    const float ocf = (float)LORG + (tg - bb) * ir;
    int o0 = (int)floorf(ocf + 0.5f) - W;
    return max(0, min(LORG - NW, o0));
}

__global__ __launch_bounds__(256) void li_fused(
    const float* __restrict__ x,      // [B, LORG, NCH]
    const float* __restrict__ rmo,    // [NCH]
    const float* __restrict__ bias,   // [NCH]
    float* __restrict__ out)          // [B, LTO, NCH]
{
    // XCD swizzle: 1344 = 8 * 168. Consecutive work ids share (t-tile) ->
    // same x rows; chunk 168 = 4 t-tiles x 21 n x 2 halves onto one XCD.
    const int h  = blockIdx.x;
    const int wk = (h & 7) * (NBLK / 8) + (h >> 3);
    const int bh = wk & 1;                 // batch half
    const int tn = wk >> 1;                // (t-tile, n)
    const int tt = tn / NCH;
    const int n  = tn - tt * NCH;
    const int t0 = tt * TT;

    const int tid = threadIdx.x;
    const int tl  = tid & 63;              // this thread's t within the tile
    const int wv  = tid >> 6;              // wave id 0..3
    const int b0  = bh * BH;

    __shared__ float xs[BH][XSTR];

    const float r  = fminf(fmaxf(rmo[n] + 1.0f, MIN_RATIO), MAX_RATIO);
    const float bb = fminf(fmaxf(bias[n], MIN_BIAS), MAX_BIAS);
    const float ir = 1.0f / r;

    // block-wide window (same for all threads; o0 monotone in t)
    const int lo  = compute_o0((float)(t0 - LTO), bb, ir);
    const int hi  = compute_o0((float)(t0 + TT - 1 - LTO), bb, ir);
    const int len = hi + NW - lo;          // <= ceil(63/0.7)+17 = 107 < XSTR

    // ---- per-thread weights for its tl (registers; amortized over b) ----
    const float tg = (float)(t0 + tl - LTO);
    const int   o0 = compute_o0(tg, bb, ir);
    const int base = o0 - lo;
    float d = (float)(o0 - LORG) * r + bb - tg;      // d_j = d + j*r
    // analytic max of -3*d_j^2 over j in [0,16]: nearest j to -d/r
    float js = floorf(-d * ir + 0.5f);
    js = fminf(fmaxf(js, 0.0f), 16.0f);
    const float dstar = d + js * r;
    const float m = NEG3LOG2E * dstar * dstar;       // log2-domain max
    float w[NW];
    float s = 0.0f;
    #pragma unroll
    for (int j = 0; j < NW; ++j) {
        const float e = NEG3LOG2E * d * d - m;       // <= 0
        w[j] = exp2f(e);                             // native v_exp_f32
        s += w[j];
        d += r;
    }
    const float inv = 1.0f / s;                      // s >= 1, no NaN

    // ---- stage 16 per-batch windows (gather, stride 84B) ----
    for (int bl = wv; bl < BH; bl += 4) {
        const float* col = x + ((size_t)((b0 + bl) * LORG + lo)) * NCH + n;
        for (int i = tl; i < len; i += 64)
            xs[bl][i] = col[(size_t)i * NCH];
    }
    __syncthreads();

    // ---- compute: 4 outputs per thread (fixed tl, 4 batches) ----
    for (int bl = wv; bl < BH; bl += 4) {
        float acc = 0.0f;
        #pragma unroll
        for (int j = 0; j < NW; ++j)
            acc = fmaf(w[j], xs[bl][base + j], acc);
        out[((size_t)(b0 + bl) * LTO + t0 + tl) * NCH + n] = acc * inv;
    }
}

extern "C" void kernel_launch(void* const* d_in, const int* in_sizes, int n_in,
                              void* d_out, int out_size, void* d_ws, size_t ws_size,
                              hipStream_t stream) {
    const float* x    = (const float*)d_in[0];
    const float* rmo  = (const float*)d_in[1];
    const float* bias = (const float*)d_in[2];
    float* out = (float*)d_out;

    li_fused<<<NBLK, 256, 0, stream>>>(x, rmo, bias, out);
}